// Round 5
// baseline (89.245 us; speedup 1.0000x reference)
//
#include <hip/hip_runtime.h>

// out[b,n] = relu( sum_d x[b, idx[n,d]] * w[n,d] )
//   x: (B=256, N=16384) f32, w: (N,32) f32, idx: (N,32) i32, out: (B,N) f32
//
// R14: occupancy attack. Evidence: R10/R11/R13 source-scheduling all null
// (R12's VGPR_Count=36 with 64 regs of declared prefetch state proves the
// compiler sinks loads -- all variants compile to the same schedule), and
// R12's counters show the hot loop <40% LDS-busy, 7% VALU, 8% HBM ->
// latency-bound. The one lever the compiler can't undo is waves/CU, pinned
// at 16 (50%) by the 128 KiB 4-batch image. Change: 2-batch b32 image
// (64 KiB) -> 2 blocks/CU = 32 waves/CU (100%), grid 512 = 128 pairs x 4
// splits. Same gathered bytes (2x b32 reads instead of 1x b64), 2x stream
// traffic (L2-resident, cheap). Per-output FP op sequence identical to
// R9-R13 (d ascending, lo/hi per pair, a=d<16 / c=d>=16 split) -> absmax
// unchanged. prep kernel and pw4 layout untouched.

#define NB   16384
#define DEG  32

typedef __fp16 hp2 __attribute__((ext_vector_type(2)));  // cvt_pkrtz result type

__device__ __forceinline__ unsigned pk16(float a, float b) {
    return __builtin_bit_cast(unsigned, (hp2)__builtin_amdgcn_cvt_pkrtz(a, b));
}

// prep: pack (idx,w) rows into 8 coalesced uint4 streams:
//   pw4[d4][n] = { idxpair(2*d4), wpair(2*d4), idxpair(2*d4+1), wpair(2*d4+1) }
__global__ __launch_bounds__(256) void prep_pw_kernel(
    const int* __restrict__ idx, const float* __restrict__ w,
    uint4* __restrict__ pw4) {
    __shared__ int   idx_s[64][33];
    __shared__ float w_s[64][33];
    const int t  = threadIdx.x;
    const int nb = (int)blockIdx.x * 64;

    const int4*   src  = (const int4*)(idx + (size_t)nb * DEG);
    const float4* srcw = (const float4*)(w   + (size_t)nb * DEG);
#pragma unroll
    for (int p = 0; p < 2; ++p) {
        const int e4 = t + 256 * p;              // int4 index 0..511, coalesced
        const int n0 = e4 >> 3;
        const int c0 = (e4 & 7) * 4;
        const int4 v = src[e4];
        idx_s[n0][c0 + 0] = v.x; idx_s[n0][c0 + 1] = v.y;
        idx_s[n0][c0 + 2] = v.z; idx_s[n0][c0 + 3] = v.w;
        const float4 f = srcw[e4];
        w_s[n0][c0 + 0] = f.x; w_s[n0][c0 + 1] = f.y;
        w_s[n0][c0 + 2] = f.z; w_s[n0][c0 + 3] = f.w;
    }
    __syncthreads();

    const int np    = t & 63;
    const int dbase = t >> 6;                    // 0..3
#pragma unroll
    for (int k = 0; k < 2; ++k) {
        const int d4 = dbase * 2 + k;            // 0..7
        const int c  = 4 * d4;                   // first of 4 d-columns
        uint4 o;
        o.x = (unsigned)idx_s[np][c + 0] | ((unsigned)idx_s[np][c + 1] << 16);
        o.y = pk16(w_s[np][c + 0], w_s[np][c + 1]);
        o.z = (unsigned)idx_s[np][c + 2] | ((unsigned)idx_s[np][c + 3] << 16);
        o.w = pk16(w_s[np][c + 2], w_s[np][c + 3]);
        pw4[(size_t)d4 * NB + nb + np] = o;
    }
}

// Load all 8 uint4 streams for column nn.
#define LOADQ(buf, nn)                                                     \
    do {                                                                   \
        const uint4* p_ = pw4 + (nn);                                      \
        _Pragma("unroll") for (int d4_ = 0; d4_ < 8; ++d4_)                \
            buf[d4_] = p_[(size_t)d4_ * NB];                               \
    } while (0)

// Issue the 4 ds_read_b32 gathers for group K (addresses from Q[K].x/.z).
#define GISSUE(K)                                                          \
    {                                                                      \
        const unsigned jA_ = Q[K].x;                                       \
        g[K][0] = lds32[jA_ & 0xffffu];                                    \
        g[K][1] = lds32[jA_ >> 16];                                        \
        const unsigned jB_ = Q[K].z;                                       \
        g[K][2] = lds32[jB_ & 0xffffu];                                    \
        g[K][3] = lds32[jB_ >> 16];                                        \
    }

// Consume group K: 4 v_pk_fma_f16 (d ascending, lo then hi per pair --
// identical per-output op sequence to R9-R13).
#define GFMA(K, r01)                                                       \
    {                                                                      \
        const hp2 wA_  = __builtin_bit_cast(hp2, Q[K].y);                  \
        const hp2 wAlo = {wA_.x, wA_.x};                                   \
        const hp2 wAhi = {wA_.y, wA_.y};                                   \
        r01 += wAlo * __builtin_bit_cast(hp2, g[K][0]);                    \
        r01 += wAhi * __builtin_bit_cast(hp2, g[K][1]);                    \
        const hp2 wB_  = __builtin_bit_cast(hp2, Q[K].w);                  \
        const hp2 wBlo = {wB_.x, wB_.x};                                   \
        const hp2 wBhi = {wB_.y, wB_.y};                                   \
        r01 += wBlo * __builtin_bit_cast(hp2, g[K][2]);                    \
        r01 += wBhi * __builtin_bit_cast(hp2, g[K][3]);                    \
    }

// One column: stream load, gather+fma, 2 NT stores.
#define STEP(I, LD)                                                        \
    {                                                                      \
        const int n = n0 + t + 1024 * (I);                                 \
        if (LD) LOADQ(Q, n);                                               \
        unsigned g[8][4];                                                  \
        GISSUE(0) GISSUE(1) GISSUE(2) GISSUE(3)                            \
        hp2 a01 = {0, 0}, c01 = {0, 0};                                    \
        GFMA(0, a01) GISSUE(4)                                             \
        GFMA(1, a01) GISSUE(5)                                             \
        GFMA(2, a01) GISSUE(6)                                             \
        GFMA(3, a01) GISSUE(7)                                             \
        GFMA(4, c01)                                                       \
        GFMA(5, c01)                                                       \
        GFMA(6, c01)                                                       \
        GFMA(7, c01)                                                       \
        const hp2 s01 = a01 + c01;                                         \
        __builtin_nontemporal_store(fmaxf((float)s01.x, 0.f),              \
                                    &out[(size_t)(b0 + 0) * NB + n]);      \
        __builtin_nontemporal_store(fmaxf((float)s01.y, 0.f),              \
                                    &out[(size_t)(b0 + 1) * NB + n]);      \
    }

__global__ __launch_bounds__(1024, 8) void gather2_kernel(
    const float* __restrict__ x, const uint4* __restrict__ pw4,
    float* __restrict__ out) {
    extern __shared__ unsigned lds32[];          // 16384 uint = 64 KiB
    const int t  = threadIdx.x;
    const int pr = (int)blockIdx.x & 127;        // row-pair 0..127 -> b = 2pr,2pr+1
    const int n0 = ((int)blockIdx.x >> 7) * 4096;  // split-major: XCD = pr%8

    // Stage pair j-image: lds32[j] = pk16(x[b0][j], x[b1][j]).
    const float* xr0 = x + (size_t)(2 * pr) * NB;
    const float* xr1 = xr0 + NB;
#pragma unroll
    for (int p = 0; p < 4; ++p) {
        const int j = 4 * (t + 1024 * p);
        const float4 r0 = *(const float4*)&xr0[j];
        const float4 r1 = *(const float4*)&xr1[j];
        uint4 w0;
        w0.x = pk16(r0.x, r1.x);
        w0.y = pk16(r0.y, r1.y);
        w0.z = pk16(r0.z, r1.z);
        w0.w = pk16(r0.w, r1.w);
        *(uint4*)&lds32[j] = w0;                 // 16B-aligned, stride-16B clean
    }

    uint4 Q[8];
    // i=0 streams issued before the barrier: latency hides under the
    // staging drain + barrier.
    LOADQ(Q, n0 + t);
    __syncthreads();

    const int b0 = 2 * pr;
    STEP(0, 0)
    STEP(1, 1)
    STEP(2, 1)
    STEP(3, 1)
}

extern "C" void kernel_launch(void* const* d_in, const int* in_sizes, int n_in,
                              void* d_out, int out_size, void* d_ws, size_t ws_size,
                              hipStream_t stream) {
    const float* x   = (const float*)d_in[0];    // (B, N)
    const float* w   = (const float*)d_in[1];    // (N, DEG)
    const int*   idx = (const int*)d_in[2];      // (N, DEG)
    float* out = (float*)d_out;                  // (B, N)
    uint4* pw4 = (uint4*)d_ws;                   // [8][N] uint4 = 2 MiB

    // allow 64 KiB dynamic LDS (idempotent; host-side, capture-safe)
    (void)hipFuncSetAttribute((const void*)gather2_kernel,
                              hipFuncAttributeMaxDynamicSharedMemorySize, 65536);

    prep_pw_kernel<<<NB / 64, 256, 0, stream>>>(idx, w, pw4);

    gather2_kernel<<<512, 1024, 65536, stream>>>(x, pw4, out);
}